// Round 12
// baseline (547.867 us; speedup 1.0000x reference)
//
#include <hip/hip_runtime.h>
#include <math.h>

// AttentionBlock: B=8, C=256, HW=4096. Round 12: 32 Q-rows/wave attention.
//   R11 (LDS-free) failed numerics -> reverted to proven R9/R10 LDS internals.
//   attn: each wave owns TWO 16-row i-subtiles sharing all K/V LDS reads
//   (halves LDS ops per Q-row, the measured bottleneck). Block=128 rows,
//   grid 512 = 8b x 32 itiles x split2, 2-way combine. XCD grid, defer-rescale.
//   K1/K1b/K2 unchanged; K4 reads combined slots.
// ws: s,t 16KB | Qt 16M | Kt 16M | Vb 16M | pO 32M (overlays nxT) | pML 0.5M

#define Bn 8
#define Cn 256
#define HWn 4096
#define Gn 8
#define CPGn 32
#define Mqkv 768
#define EPSf 1e-5f
#define QSCALEf 0.0625f   // 1/sqrt(256), exact in bf16
#define RTHR 8.0f

typedef short bf16x8 __attribute__((ext_vector_type(8)));
typedef float f32x4 __attribute__((ext_vector_type(4)));

__device__ __forceinline__ unsigned short f2bf(float f) {
  union { float f; unsigned u; } v; v.f = f;
  unsigned r = v.u + 0x7FFFu + ((v.u >> 16) & 1u);  // RNE
  return (unsigned short)(r >> 16);
}

__device__ __forceinline__ float bf2f(unsigned short u) {
  union { unsigned u; float f; } v; v.u = ((unsigned)u) << 16;
  return v.f;
}

__device__ __forceinline__ int cvt_pk_bf16(float lo, float hi) {
  int d;
  asm("v_cvt_pk_bf16_f32 %0, %1, %2" : "=v"(d) : "v"(lo), "v"(hi));
  return d;
}

// ---------------- K1: group-norm stats -> per-channel affine ----------------
__global__ __launch_bounds__(1024)
void gn_stats_kernel(const float* __restrict__ x, const float* __restrict__ gn_w,
                     const float* __restrict__ gn_b, float* __restrict__ s_out,
                     float* __restrict__ t_out) {
  const int b = blockIdx.x / Gn, g = blockIdx.x % Gn;
  const float4* base = (const float4*)(x + ((size_t)(b * Cn + g * CPGn)) * HWn);
  const int n4 = CPGn * HWn / 4;
  float sum = 0.f, sq = 0.f;
  for (int i = threadIdx.x; i < n4; i += 1024) {
    float4 v = base[i];
    sum += (v.x + v.y) + (v.z + v.w);
    sq  += (v.x * v.x + v.y * v.y) + (v.z * v.z + v.w * v.w);
  }
  __shared__ float ss[1024], s2[1024];
  ss[threadIdx.x] = sum; s2[threadIdx.x] = sq;
  __syncthreads();
  for (int off = 512; off > 0; off >>= 1) {
    if ((int)threadIdx.x < off) {
      ss[threadIdx.x] += ss[threadIdx.x + off];
      s2[threadIdx.x] += s2[threadIdx.x + off];
    }
    __syncthreads();
  }
  if (threadIdx.x < CPGn) {
    const float inv_n = 1.f / (float)(CPGn * HWn);
    float mean = ss[0] * inv_n;
    float var  = s2[0] * inv_n - mean * mean;
    float rstd = rsqrtf(var + EPSf);
    int c = g * CPGn + (int)threadIdx.x;
    float sc = gn_w[c] * rstd;
    s_out[b * Cn + c] = sc;
    t_out[b * Cn + c] = gn_b[c] - mean * sc;
  }
}

// ---------------- K1b: affine + transpose -> nxT[b][n][c] bf16 ----------------
__global__ __launch_bounds__(256)
void affine_transpose_kernel(const float* __restrict__ x, const float* __restrict__ s_aff,
                             const float* __restrict__ t_aff, unsigned short* __restrict__ nxT) {
  const int bid = blockIdx.x;
  const int b = bid & 7, r = bid >> 3;
  const int c0 = (r & 3) * 64, n0 = (r >> 2) * 64;
  const int tid = threadIdx.x;
  __shared__ unsigned int ld32[64][33];
  const float* xb = x + ((size_t)(b * Cn + c0)) * HWn + n0;
  const int cl0 = tid >> 4, nn = (tid & 15) * 4;
#pragma unroll
  for (int it = 0; it < 4; ++it) {
    int cl = cl0 + 16 * it;
    int c = c0 + cl;
    float sc = s_aff[b * Cn + c], sh = t_aff[b * Cn + c];
    float4 v = *(const float4*)(xb + (size_t)cl * HWn + nn);
    ld32[cl][(nn >> 1) + 0] = (unsigned)cvt_pk_bf16(v.x * sc + sh, v.y * sc + sh);
    ld32[cl][(nn >> 1) + 1] = (unsigned)cvt_pk_bf16(v.z * sc + sh, v.w * sc + sh);
  }
  __syncthreads();
#pragma unroll
  for (int it = 0; it < 2; ++it) {
    int chunk = tid + 256 * it;
    int n = chunk >> 3, cg = chunk & 7;
    union { unsigned short u[8]; bf16x8 v; } o;
#pragma unroll
    for (int k = 0; k < 8; ++k) {
      unsigned w32 = ld32[cg * 8 + k][n >> 1];
      o.u[k] = (unsigned short)((n & 1) ? (w32 >> 16) : (w32 & 0xffffu));
    }
    *(bf16x8*)(nxT + ((size_t)(b * HWn + n0 + n)) * Cn + c0 + cg * 8) = o.v;
  }
}

// ---------------- K2: QKV GEMM, LDS-free bf16 MFMA ----------------
__global__ __launch_bounds__(256, 2)
void qkv_gemm_kernel(const unsigned short* __restrict__ nxT, const float* __restrict__ w,
                     const float* __restrict__ wb, unsigned short* __restrict__ Qt,
                     unsigned short* __restrict__ Kt, unsigned short* __restrict__ Vb) {
  const int bid = blockIdx.x;
  const int b = bid & 7, r = bid >> 3;
  const int n0 = (r & 63) * 64, m0 = (r >> 6) * 128;
  const int tid = threadIdx.x;
  const int wv = tid >> 6, l = tid & 63;
  const int l15 = l & 15, lq = l >> 4;
  const int ob = m0 + wv * 32;

  bf16x8 wf[2][8];
#pragma unroll
  for (int g = 0; g < 2; ++g) {
    const float* wr = w + (size_t)(ob + g * 16 + l15) * Cn + lq * 8;
#pragma unroll
    for (int kc = 0; kc < 8; ++kc) {
      float4 a = *(const float4*)(wr + kc * 32);
      float4 c4 = *(const float4*)(wr + kc * 32 + 4);
      union { int w4[4]; bf16x8 v; } u;
      u.w4[0] = cvt_pk_bf16(a.x, a.y);  u.w4[1] = cvt_pk_bf16(a.z, a.w);
      u.w4[2] = cvt_pk_bf16(c4.x, c4.y); u.w4[3] = cvt_pk_bf16(c4.z, c4.w);
      wf[g][kc] = u.v;
    }
  }

  const unsigned short* nb = nxT + (size_t)b * HWn * Cn + lq * 8;
  f32x4 acc[2][4];
#pragma unroll
  for (int g = 0; g < 2; ++g)
#pragma unroll
    for (int s = 0; s < 4; ++s) acc[g][s] = (f32x4)(0.f);

  const bool isV = (m0 >= 512);
#pragma unroll
  for (int s = 0; s < 4; ++s) {
    const unsigned short* np = nb + (size_t)(n0 + s * 16 + l15) * Cn;
#pragma unroll
    for (int kc = 0; kc < 8; ++kc) {
      bf16x8 xf = *(const bf16x8*)(np + kc * 32);
      if (!isV) {
        acc[0][s] = __builtin_amdgcn_mfma_f32_16x16x32_bf16(wf[0][kc], xf, acc[0][s], 0, 0, 0);
        acc[1][s] = __builtin_amdgcn_mfma_f32_16x16x32_bf16(wf[1][kc], xf, acc[1][s], 0, 0, 0);
      } else {
        acc[0][s] = __builtin_amdgcn_mfma_f32_16x16x32_bf16(xf, wf[0][kc], acc[0][s], 0, 0, 0);
        acc[1][s] = __builtin_amdgcn_mfma_f32_16x16x32_bf16(xf, wf[1][kc], acc[1][s], 0, 0, 0);
      }
    }
  }

  if (!isV) {
    unsigned short* dst = (m0 < 256) ? Qt : Kt;
    const float scl = (m0 < 256) ? QSCALEf : 1.0f;
#pragma unroll
    for (int g = 0; g < 2; ++g) {
      int cb = ((ob + g * 16) & 255) + lq * 4;
      float b0 = wb[ob + g * 16 + lq * 4 + 0];
      float b1 = wb[ob + g * 16 + lq * 4 + 1];
      float b2 = wb[ob + g * 16 + lq * 4 + 2];
      float b3 = wb[ob + g * 16 + lq * 4 + 3];
#pragma unroll
      for (int s = 0; s < 4; ++s) {
        int n = n0 + s * 16 + l15;
        ushort4 pk;
        pk.x = f2bf((acc[g][s][0] + b0) * scl);
        pk.y = f2bf((acc[g][s][1] + b1) * scl);
        pk.z = f2bf((acc[g][s][2] + b2) * scl);
        pk.w = f2bf((acc[g][s][3] + b3) * scl);
        *(ushort4*)(dst + ((size_t)(b * HWn + n)) * Cn + cb) = pk;
      }
    }
  } else {
#pragma unroll
    for (int g = 0; g < 2; ++g) {
      int o = ob + g * 16 + l15;
      int c = o - 512;
      float bias = wb[o];
#pragma unroll
      for (int s = 0; s < 4; ++s) {
        int n = n0 + s * 16 + lq * 4;
        ushort4 pk;
        pk.x = f2bf(acc[g][s][0] + bias);
        pk.y = f2bf(acc[g][s][1] + bias);
        pk.z = f2bf(acc[g][s][2] + bias);
        pk.w = f2bf(acc[g][s][3] + bias);
        *(ushort4*)(Vb + ((size_t)(b * Cn + c)) * HWn + n) = pk;
      }
    }
  }
}

// ---------------- K3: flash attention, 32 Q rows/wave, split-2 ----------------
// grid 512: b=bid&7, part=(bid>>3)&1, itile=bid>>4, i0=itile*128; j-range part*2048+[0,2048).
// Wave wv: rows i0+wv*32+{0..31} as two 16-row subtiles (A: +l15, B: +16+l15),
// sharing every K/V LDS read. LDS chunk-linear 16KB K + 16KB V (R8 maps).
__global__ __launch_bounds__(256, 2)
void attn_kernel(const unsigned short* __restrict__ Qt,
                 const unsigned short* __restrict__ Kt,
                 const unsigned short* __restrict__ Vb,
                 unsigned short* __restrict__ pO, float* __restrict__ pML) {
  const int bid = blockIdx.x;
  const int b = bid & 7, part = (bid >> 3) & 1, i0 = (bid >> 4) * 128;
  const int tid = threadIdx.x;
  const int wv = tid >> 6, l = tid & 63;
  const int l15 = l & 15, lq = l >> 4;

  __shared__ unsigned short Ks[8192];  // 16KB
  __shared__ unsigned short Vs[8192];  // 16KB
  char* KsB = (char*)Ks;
  char* VsB = (char*)Vs;

  const unsigned short* Qb = Qt + ((size_t)b * HWn + i0) * Cn;
  const unsigned short* Kb = Kt + (size_t)b * HWn * Cn;
  const unsigned short* Vg = Vb + (size_t)b * Cn * HWn;

  // hoisted Q fragments, both subtiles (prescaled by 1/16)
  bf16x8 qfA[8], qfB[8];
  {
    const unsigned short* qr0 = Qb + (size_t)(wv * 32 + l15) * Cn + lq * 8;
    const unsigned short* qr1 = qr0 + 16 * Cn;
#pragma unroll
    for (int kc = 0; kc < 8; ++kc) {
      qfA[kc] = *(const bf16x8*)(qr0 + kc * 32);
      qfB[kc] = *(const bf16x8*)(qr1 + kc * 32);
    }
  }

  // staging maps (R8): thread tid owns chunks q*256+tid, q=0..3
  const int jk = ((tid >> 6) & 1) * 16 + (tid & 15);
  const int ck = (tid >> 7) * 32 + ((tid >> 4) & 3) * 8;
  const int cv = (tid >> 6) * 16 + (tid & 15);
  const int jv = ((tid >> 4) & 3) * 8;
  const unsigned short* gK = Kb + (size_t)(jk + part * 2048) * Cn + ck;
  const unsigned short* gV = Vg + (size_t)cv * HWn + jv + part * 2048;

  const int laneA = l15 + ((lq & 1) << 5);
  const int laneB = laneA + 16;
  const int shi = lq >> 1;

  bf16x8 kst[4], vst[4];
#pragma unroll
  for (int q = 0; q < 4; ++q) kst[q] = *(const bf16x8*)(gK + q * 64);
#pragma unroll
  for (int q = 0; q < 4; ++q) vst[q] = *(const bf16x8*)(gV + (size_t)q * 64 * HWn);
  gK += 32 * Cn; gV += 32;

  f32x4 oA[16], oB[16];
#pragma unroll
  for (int cs = 0; cs < 16; ++cs) { oA[cs] = (f32x4)(0.f); oB[cs] = (f32x4)(0.f); }
  float mA = -INFINITY, lA = 0.f, mB = -INFINITY, lB = 0.f;

#pragma unroll 1
  for (int t = 0; t < 64; ++t) {
#pragma unroll
    for (int q = 0; q < 4; ++q) *(bf16x8*)(KsB + tid * 16 + q * 4096) = kst[q];
#pragma unroll
    for (int q = 0; q < 4; ++q) *(bf16x8*)(VsB + tid * 16 + q * 4096) = vst[q];
    __syncthreads();
    if (t < 63) {
#pragma unroll
      for (int q = 0; q < 4; ++q) kst[q] = *(const bf16x8*)(gK + q * 64);
#pragma unroll
      for (int q = 0; q < 4; ++q) vst[q] = *(const bf16x8*)(gV + (size_t)q * 64 * HWn);
      gK += 32 * Cn; gV += 32;
    }

    // ---- S^T = K Q^T for both subtiles (shared kf reads) ----
    f32x4 sA0 = (f32x4)(0.f), sA1 = (f32x4)(0.f);
    f32x4 sB0 = (f32x4)(0.f), sB1 = (f32x4)(0.f);
#pragma unroll
    for (int kc = 0; kc < 8; ++kc) {
      bf16x8 kf0 = *(const bf16x8*)(KsB + l * 16 + kc * 2048);
      bf16x8 kf1 = *(const bf16x8*)(KsB + l * 16 + kc * 2048 + 1024);
      sA0 = __builtin_amdgcn_mfma_f32_16x16x32_bf16(kf0, qfA[kc], sA0, 0, 0, 0);
      sA1 = __builtin_amdgcn_mfma_f32_16x16x32_bf16(kf1, qfA[kc], sA1, 0, 0, 0);
      sB0 = __builtin_amdgcn_mfma_f32_16x16x32_bf16(kf0, qfB[kc], sB0, 0, 0, 0);
      sB1 = __builtin_amdgcn_mfma_f32_16x16x32_bf16(kf1, qfB[kc], sB1, 0, 0, 0);
    }

    // ---- softmax subtile A (rows l15) ----
    {
      float p0[4], p1[4];
#pragma unroll
      for (int u = 0; u < 4; ++u) { p0[u] = sA0[u]; p1[u] = sA1[u]; }
      float rm = fmaxf(fmaxf(fmaxf(p0[0], p0[1]), fmaxf(p0[2], p0[3])),
                       fmaxf(fmaxf(p1[0], p1[1]), fmaxf(p1[2], p1[3])));
      rm = fmaxf(rm, __shfl_xor(rm, 16));
      rm = fmaxf(rm, __shfl_xor(rm, 32));
      if (!__all(rm - mA <= RTHR)) {
        float mn = fmaxf(mA, rm);
        float alpha = __expf(mA - mn);
        mA = mn; lA *= alpha;
        float a0 = __shfl(alpha, 4 * lq + 0);
        float a1 = __shfl(alpha, 4 * lq + 1);
        float a2 = __shfl(alpha, 4 * lq + 2);
        float a3 = __shfl(alpha, 4 * lq + 3);
#pragma unroll
        for (int cs = 0; cs < 16; ++cs) {
          oA[cs][0] *= a0; oA[cs][1] *= a1; oA[cs][2] *= a2; oA[cs][3] *= a3;
        }
      }
      float rs = 0.f;
#pragma unroll
      for (int u = 0; u < 4; ++u) { p0[u] = __expf(p0[u] - mA); rs += p0[u]; }
#pragma unroll
      for (int u = 0; u < 4; ++u) { p1[u] = __expf(p1[u] - mA); rs += p1[u]; }
      rs += __shfl_xor(rs, 16);
      rs += __shfl_xor(rs, 32);
      lA += rs;

      int d00 = cvt_pk_bf16(p0[0], p0[1]), d01 = cvt_pk_bf16(p0[2], p0[3]);
      int d10 = cvt_pk_bf16(p1[0], p1[1]), d11 = cvt_pk_bf16(p1[2], p1[3]);
      int A00 = __shfl(d00, laneA), A01 = __shfl(d01, laneA);
      int A10 = __shfl(d10, laneA), A11 = __shfl(d11, laneA);
      int B00 = __shfl(d00, laneB), B01 = __shfl(d01, laneB);
      int B10 = __shfl(d10, laneB), B11 = __shfl(d11, laneB);
      union { int w[4]; bf16x8 v; } pa;
      pa.w[0] = shi ? A10 : A00; pa.w[1] = shi ? A11 : A01;
      pa.w[2] = shi ? B10 : B00; pa.w[3] = shi ? B11 : B01;
      // PV for A is fused below with shared vf reads; store pa in a var
      // (kept in scope via the union)
      // ---- softmax subtile B (rows 16+l15) ----
      float q0[4], q1[4];
#pragma unroll
      for (int u = 0; u < 4; ++u) { q0[u] = sB0[u]; q1[u] = sB1[u]; }
      float rmb = fmaxf(fmaxf(fmaxf(q0[0], q0[1]), fmaxf(q0[2], q0[3])),
                        fmaxf(fmaxf(q1[0], q1[1]), fmaxf(q1[2], q1[3])));
      rmb = fmaxf(rmb, __shfl_xor(rmb, 16));
      rmb = fmaxf(rmb, __shfl_xor(rmb, 32));
      if (!__all(rmb - mB <= RTHR)) {
        float mn = fmaxf(mB, rmb);
        float alpha = __expf(mB - mn);
        mB = mn; lB *= alpha;
        float a0 = __shfl(alpha, 4 * lq + 0);
        float a1 = __shfl(alpha, 4 * lq + 1);
        float a2 = __shfl(alpha, 4 * lq + 2);
        float a3 = __shfl(alpha, 4 * lq + 3);
#pragma unroll
        for (int cs = 0; cs < 16; ++cs) {
          oB[cs][0] *= a0; oB[cs][1] *= a1; oB[cs][2] *= a2; oB[cs][3] *= a3;
        }
      }
      float rsb = 0.f;
#pragma unroll
      for (int u = 0; u < 4; ++u) { q0[u] = __expf(q0[u] - mB); rsb += q0[u]; }
#pragma unroll
      for (int u = 0; u < 4; ++u) { q1[u] = __expf(q1[u] - mB); rsb += q1[u]; }
      rsb += __shfl_xor(rsb, 16);
      rsb += __shfl_xor(rsb, 32);
      lB += rsb;

      int e00 = cvt_pk_bf16(q0[0], q0[1]), e01 = cvt_pk_bf16(q0[2], q0[3]);
      int e10 = cvt_pk_bf16(q1[0], q1[1]), e11 = cvt_pk_bf16(q1[2], q1[3]);
      int C00 = __shfl(e00, laneA), C01 = __shfl(e01, laneA);
      int C10 = __shfl(e10, laneA), C11 = __shfl(e11, laneA);
      int D00 = __shfl(e00, laneB), D01 = __shfl(e01, laneB);
      int D10 = __shfl(e10, laneB), D11 = __shfl(e11, laneB);
      union { int w[4]; bf16x8 v; } pb;
      pb.w[0] = shi ? C10 : C00; pb.w[1] = shi ? C11 : C01;
      pb.w[2] = shi ? D10 : D00; pb.w[3] = shi ? D11 : D01;

      // ---- O += P V, both subtiles sharing vf reads ----
#pragma unroll
      for (int cs = 0; cs < 16; ++cs) {
        bf16x8 vf = *(const bf16x8*)(VsB + l * 16 + cs * 1024);
        oA[cs] = __builtin_amdgcn_mfma_f32_16x16x32_bf16(pa.v, vf, oA[cs], 0, 0, 0);
        oB[cs] = __builtin_amdgcn_mfma_f32_16x16x32_bf16(pb.v, vf, oB[cs], 0, 0, 0);
      }
    }
    __syncthreads();
  }

  // ---- epilogue: store UNNORMALIZED partials [row][c] bf16 + (m,l) ----
  unsigned short* pOb = pO + (size_t)bid * (128 * 256);
  const int rA = wv * 32 + lq * 4;   // subtile A local rows
  const int rB = rA + 16;            // subtile B
#pragma unroll
  for (int cs = 0; cs < 16; ++cs) {
    int c = cs * 16 + l15;
    pOb[(rA + 0) * 256 + c] = f2bf(oA[cs][0]);
    pOb[(rA + 1) * 256 + c] = f2bf(oA[cs][1]);
    pOb[(rA + 2) * 256 + c] = f2bf(oA[cs][2]);
    pOb[(rA + 3) * 256 + c] = f2bf(oA[cs][3]);
    pOb[(rB + 0) * 256 + c] = f2bf(oB[cs][0]);
    pOb[(rB + 1) * 256 + c] = f2bf(oB[cs][1]);
    pOb[(rB + 2) * 256 + c] = f2bf(oB[cs][2]);
    pOb[(rB + 3) * 256 + c] = f2bf(oB[cs][3]);
  }
  if (lq == 0) {
    pML[(size_t)bid * 256 + (wv * 32 + l15) * 2 + 0] = mA;
    pML[(size_t)bid * 256 + (wv * 32 + l15) * 2 + 1] = lA;
    pML[(size_t)bid * 256 + (wv * 32 + 16 + l15) * 2 + 0] = mB;
    pML[(size_t)bid * 256 + (wv * 32 + 16 + l15) * 2 + 1] = lB;
  }
}

// ---------------- K3b: combine 2 partials in place into part-0 slot ----------------
// grid 256: b=bid&7, itile=bid>>3. slot(p) = b + p*8 + itile*16.
__global__ __launch_bounds__(256)
void attn_combine_kernel(unsigned short* __restrict__ pO, const float* __restrict__ pML) {
  const int bid = blockIdx.x;
  const int b = bid & 7, itile = bid >> 3;
  const int tid = threadIdx.x;
  const int p0 = b + itile * 16, p1 = p0 + 8;
  unsigned short* B0 = pO + (size_t)p0 * (128 * 256);
  const unsigned short* B1 = pO + (size_t)p1 * (128 * 256);

  __shared__ float g0S[128], g1S[128];
  if (tid < 128) {
    float m0 = pML[(size_t)p0 * 256 + tid * 2], l0 = pML[(size_t)p0 * 256 + tid * 2 + 1];
    float m1 = pML[(size_t)p1 * 256 + tid * 2], l1 = pML[(size_t)p1 * 256 + tid * 2 + 1];
    float ms = fmaxf(m0, m1);
    float w0 = __expf(m0 - ms), w1 = __expf(m1 - ms);
    float id = 1.f / (w0 * l0 + w1 * l1);
    g0S[tid] = w0 * id; g1S[tid] = w1 * id;
  }
  __syncthreads();

#pragma unroll
  for (int k = 0; k < 16; ++k) {
    int chunk = tid + 256 * k;
    int row = chunk >> 5, cc = (chunk & 31) * 8;
    int off = row * 256 + cc;
    float g0 = g0S[row], g1 = g1S[row];
    union { unsigned short u[8]; bf16x8 v; } v0, v1, o;
    v0.v = *(const bf16x8*)(B0 + off);
    v1.v = *(const bf16x8*)(B1 + off);
#pragma unroll
    for (int e = 0; e < 8; ++e)
      o.u[e] = f2bf(g0 * bf2f(v0.u[e]) + g1 * bf2f(v1.u[e]));
    *(bf16x8*)(B0 + off) = o.v;
  }
}

// ---------------- K4: out projection, LDS-free bf16 MFMA (swapped) + residual ----------------
// Reads combined attention from pO part-0 slots: rows n -> slot b + (n>>7)*16, row n&127.
__global__ __launch_bounds__(256, 2)
void out_gemm_kernel(const unsigned short* __restrict__ pO, const float* __restrict__ w,
                     const float* __restrict__ wb, const float* __restrict__ xres,
                     float* __restrict__ y) {
  const int bid = blockIdx.x;
  const int b = bid & 7, r = bid >> 3;
  const int n0 = (r & 63) * 64, m0 = (r >> 6) * 128;
  const int tid = threadIdx.x;
  const int wv = tid >> 6, l = tid & 63;
  const int l15 = l & 15, lq = l >> 4;
  const int ob = m0 + wv * 32;

  bf16x8 wf[2][8];
#pragma unroll
  for (int g = 0; g < 2; ++g) {
    const float* wr = w + (size_t)(ob + g * 16 + l15) * Cn + lq * 8;
#pragma unroll
    for (int kc = 0; kc < 8; ++kc) {
      float4 a = *(const float4*)(wr + kc * 32);
      float4 c4 = *(const float4*)(wr + kc * 32 + 4);
      union { int w4[4]; bf16x8 v; } u;
      u.w4[0] = cvt_pk_bf16(a.x, a.y);  u.w4[1] = cvt_pk_bf16(a.z, a.w);
      u.w4[2] = cvt_pk_bf16(c4.x, c4.y); u.w4[3] = cvt_pk_bf16(c4.z, c4.w);
      wf[g][kc] = u.v;
    }
  }

  const int slot = b + ((n0 >> 7) << 4);
  const unsigned short* tb = pO + (size_t)slot * (128 * 256) + (size_t)(n0 & 127) * 256 + lq * 8;
  f32x4 acc[2][4];
#pragma unroll
  for (int g = 0; g < 2; ++g)
#pragma unroll
    for (int s = 0; s < 4; ++s) acc[g][s] = (f32x4)(0.f);

#pragma unroll
  for (int s = 0; s < 4; ++s) {
    const unsigned short* tp = tb + (size_t)(s * 16 + l15) * 256;
#pragma unroll
    for (int kc = 0; kc < 8; ++kc) {
      bf16x8 tf = *(const bf16x8*)(tp + kc * 32);
      acc[0][s] = __builtin_amdgcn_mfma_f32_16x16x32_bf16(tf, wf[0][kc], acc[0][s], 0, 0, 0);
      acc[1][s] = __builtin_amdgcn_mfma_f32_16x16x32_bf16(tf, wf[1][kc], acc[1][s], 0, 0, 0);
    }
  }

#pragma unroll
  for (int g = 0; g < 2; ++g) {
    int o = ob + g * 16 + l15;
    float bias = wb[o];
#pragma unroll
    for (int s = 0; s < 4; ++s) {
      int n = n0 + s * 16 + lq * 4;
      size_t idx = ((size_t)(b * Cn + o)) * HWn + n;
      float4 xr = *(const float4*)(xres + idx);
      float4 out;
      out.x = acc[g][s][0] + bias + xr.x;
      out.y = acc[g][s][1] + bias + xr.y;
      out.z = acc[g][s][2] + bias + xr.z;
      out.w = acc[g][s][3] + bias + xr.w;
      *(float4*)(y + idx) = out;
    }
  }
}

extern "C" void kernel_launch(void* const* d_in, const int* in_sizes, int n_in,
                              void* d_out, int out_size, void* d_ws, size_t ws_size,
                              hipStream_t stream) {
  (void)in_sizes; (void)n_in; (void)out_size; (void)ws_size;
  const float* x     = (const float*)d_in[0];
  const float* gn_w  = (const float*)d_in[1];
  const float* gn_b  = (const float*)d_in[2];
  const float* qkv_w = (const float*)d_in[3];
  const float* qkv_b = (const float*)d_in[4];
  const float* out_w = (const float*)d_in[5];
  const float* out_b = (const float*)d_in[6];
  float* out = (float*)d_out;

  char* ws = (char*)d_ws;
  const size_t BHC = (size_t)Bn * HWn * Cn;      // 8M elements
  float* s_aff = (float*)ws;
  float* t_aff = s_aff + Bn * Cn;
  unsigned short* Qt  = (unsigned short*)(ws + 16384);   // 16MB
  unsigned short* Kt  = Qt + BHC;                        // 16MB
  unsigned short* Vb  = Kt + BHC;                        // 16MB
  unsigned short* nxT = Vb + BHC;                        // 16MB (dead after qkv)
  unsigned short* pO  = nxT;                             // overlays nxT; 512*32768*2B = 32MB
  float* pML = (float*)((char*)pO + (size_t)512 * 32768 * 2);  // 512KB

  gn_stats_kernel<<<dim3(Bn * Gn), 1024, 0, stream>>>(x, gn_w, gn_b, s_aff, t_aff);
  affine_transpose_kernel<<<dim3(2048), 256, 0, stream>>>(x, s_aff, t_aff, nxT);
  qkv_gemm_kernel<<<dim3(3072), 256, 0, stream>>>(nxT, qkv_w, qkv_b, Qt, Kt, Vb);
  attn_kernel<<<dim3(512), 256, 0, stream>>>(Qt, Kt, Vb, pO, pML);
  attn_combine_kernel<<<dim3(256), 256, 0, stream>>>(pO, pML);
  out_gemm_kernel<<<dim3(1024), 256, 0, stream>>>(pO, out_w, out_b, x, out);
}

// Round 13
// 397.197 us; speedup vs baseline: 1.3793x; 1.3793x over previous
//
#include <hip/hip_runtime.h>
#include <math.h>

// AttentionBlock: B=8, C=256, HW=4096. Round 13: re-baseline = R9 verbatim
// (best passing config, 397us). R11 (LDS-free) failed numerics; R12 (32 rows/wave)
// spilled (VGPR 128 cap, 769MB scratch). attn's 272us sits at ~91% of its
// LDS-issue structural model; reverting to the proven anchor.
//   K1  gn_stats: per-(b,group) stats -> per-(b,c) affine s,t
//   K1b affine_transpose: nxT[b][n][c] bf16 (GN applied)
//   K2  qkv_gemm: LDS-free bf16 MFMA -> Qt/Kt [n][c], Vb [c][n]
//   K3  attn: flash attention, chunk-linear LDS, in-reg softmax, defer-rescale,
//       XCD grid (b=bid&7); epilogue writes tmpT[n][c] bf16
//   K4  out_gemm: LDS-free bf16 MFMA (swapped) + bias + residual
// ws: s,t 16KB | Qt 16M | Kt 16M | Vb 16M | nxT 16M | tmpT 16M

#define Bn 8
#define Cn 256
#define HWn 4096
#define Gn 8
#define CPGn 32
#define Mqkv 768
#define EPSf 1e-5f
#define QSCALEf 0.0625f   // 1/sqrt(256), exact in bf16
#define RTHR 8.0f

typedef short bf16x8 __attribute__((ext_vector_type(8)));
typedef float f32x4 __attribute__((ext_vector_type(4)));

__device__ __forceinline__ unsigned short f2bf(float f) {
  union { float f; unsigned u; } v; v.f = f;
  unsigned r = v.u + 0x7FFFu + ((v.u >> 16) & 1u);  // RNE
  return (unsigned short)(r >> 16);
}

__device__ __forceinline__ int cvt_pk_bf16(float lo, float hi) {
  int d;
  asm("v_cvt_pk_bf16_f32 %0, %1, %2" : "=v"(d) : "v"(lo), "v"(hi));
  return d;
}

// ---------------- K1: group-norm stats -> per-channel affine ----------------
__global__ __launch_bounds__(1024)
void gn_stats_kernel(const float* __restrict__ x, const float* __restrict__ gn_w,
                     const float* __restrict__ gn_b, float* __restrict__ s_out,
                     float* __restrict__ t_out) {
  const int b = blockIdx.x / Gn, g = blockIdx.x % Gn;
  const float4* base = (const float4*)(x + ((size_t)(b * Cn + g * CPGn)) * HWn);
  const int n4 = CPGn * HWn / 4;
  float sum = 0.f, sq = 0.f;
  for (int i = threadIdx.x; i < n4; i += 1024) {
    float4 v = base[i];
    sum += (v.x + v.y) + (v.z + v.w);
    sq  += (v.x * v.x + v.y * v.y) + (v.z * v.z + v.w * v.w);
  }
  __shared__ float ss[1024], s2[1024];
  ss[threadIdx.x] = sum; s2[threadIdx.x] = sq;
  __syncthreads();
  for (int off = 512; off > 0; off >>= 1) {
    if ((int)threadIdx.x < off) {
      ss[threadIdx.x] += ss[threadIdx.x + off];
      s2[threadIdx.x] += s2[threadIdx.x + off];
    }
    __syncthreads();
  }
  if (threadIdx.x < CPGn) {
    const float inv_n = 1.f / (float)(CPGn * HWn);
    float mean = ss[0] * inv_n;
    float var  = s2[0] * inv_n - mean * mean;
    float rstd = rsqrtf(var + EPSf);
    int c = g * CPGn + (int)threadIdx.x;
    float sc = gn_w[c] * rstd;
    s_out[b * Cn + c] = sc;
    t_out[b * Cn + c] = gn_b[c] - mean * sc;
  }
}

// ---------------- K1b: affine + transpose -> nxT[b][n][c] bf16 ----------------
__global__ __launch_bounds__(256)
void affine_transpose_kernel(const float* __restrict__ x, const float* __restrict__ s_aff,
                             const float* __restrict__ t_aff, unsigned short* __restrict__ nxT) {
  const int bid = blockIdx.x;
  const int b = bid & 7, r = bid >> 3;
  const int c0 = (r & 3) * 64, n0 = (r >> 2) * 64;
  const int tid = threadIdx.x;
  __shared__ unsigned int ld32[64][33];   // [c][n/2] packed bf16 pairs, padded
  const float* xb = x + ((size_t)(b * Cn + c0)) * HWn + n0;
  const int cl0 = tid >> 4, nn = (tid & 15) * 4;
#pragma unroll
  for (int it = 0; it < 4; ++it) {
    int cl = cl0 + 16 * it;
    int c = c0 + cl;
    float sc = s_aff[b * Cn + c], sh = t_aff[b * Cn + c];
    float4 v = *(const float4*)(xb + (size_t)cl * HWn + nn);
    ld32[cl][(nn >> 1) + 0] = (unsigned)cvt_pk_bf16(v.x * sc + sh, v.y * sc + sh);
    ld32[cl][(nn >> 1) + 1] = (unsigned)cvt_pk_bf16(v.z * sc + sh, v.w * sc + sh);
  }
  __syncthreads();
#pragma unroll
  for (int it = 0; it < 2; ++it) {
    int chunk = tid + 256 * it;
    int n = chunk >> 3, cg = chunk & 7;
    union { unsigned short u[8]; bf16x8 v; } o;
#pragma unroll
    for (int k = 0; k < 8; ++k) {
      unsigned w32 = ld32[cg * 8 + k][n >> 1];
      o.u[k] = (unsigned short)((n & 1) ? (w32 >> 16) : (w32 & 0xffffu));
    }
    *(bf16x8*)(nxT + ((size_t)(b * HWn + n0 + n)) * Cn + c0 + cg * 8) = o.v;
  }
}

// ---------------- K2: QKV GEMM, LDS-free bf16 MFMA ----------------
// grid 3072: b=bid&7; r=bid>>3: n0=(r&63)*64, m0=(r>>6)*128 (o-tile of 128, 4 waves x 32 o).
__global__ __launch_bounds__(256, 2)
void qkv_gemm_kernel(const unsigned short* __restrict__ nxT, const float* __restrict__ w,
                     const float* __restrict__ wb, unsigned short* __restrict__ Qt,
                     unsigned short* __restrict__ Kt, unsigned short* __restrict__ Vb) {
  const int bid = blockIdx.x;
  const int b = bid & 7, r = bid >> 3;
  const int n0 = (r & 63) * 64, m0 = (r >> 6) * 128;
  const int tid = threadIdx.x;
  const int wv = tid >> 6, l = tid & 63;
  const int l15 = l & 15, lq = l >> 4;
  const int ob = m0 + wv * 32;

  bf16x8 wf[2][8];
#pragma unroll
  for (int g = 0; g < 2; ++g) {
    const float* wr = w + (size_t)(ob + g * 16 + l15) * Cn + lq * 8;
#pragma unroll
    for (int kc = 0; kc < 8; ++kc) {
      float4 a = *(const float4*)(wr + kc * 32);
      float4 c4 = *(const float4*)(wr + kc * 32 + 4);
      union { int w4[4]; bf16x8 v; } u;
      u.w4[0] = cvt_pk_bf16(a.x, a.y);  u.w4[1] = cvt_pk_bf16(a.z, a.w);
      u.w4[2] = cvt_pk_bf16(c4.x, c4.y); u.w4[3] = cvt_pk_bf16(c4.z, c4.w);
      wf[g][kc] = u.v;
    }
  }

  const unsigned short* nb = nxT + (size_t)b * HWn * Cn + lq * 8;
  f32x4 acc[2][4];
#pragma unroll
  for (int g = 0; g < 2; ++g)
#pragma unroll
    for (int s = 0; s < 4; ++s) acc[g][s] = (f32x4)(0.f);

  const bool isV = (m0 >= 512);
#pragma unroll
  for (int s = 0; s < 4; ++s) {
    const unsigned short* np = nb + (size_t)(n0 + s * 16 + l15) * Cn;
#pragma unroll
    for (int kc = 0; kc < 8; ++kc) {
      bf16x8 xf = *(const bf16x8*)(np + kc * 32);
      if (!isV) {
        acc[0][s] = __builtin_amdgcn_mfma_f32_16x16x32_bf16(wf[0][kc], xf, acc[0][s], 0, 0, 0);
        acc[1][s] = __builtin_amdgcn_mfma_f32_16x16x32_bf16(wf[1][kc], xf, acc[1][s], 0, 0, 0);
      } else {
        acc[0][s] = __builtin_amdgcn_mfma_f32_16x16x32_bf16(xf, wf[0][kc], acc[0][s], 0, 0, 0);
        acc[1][s] = __builtin_amdgcn_mfma_f32_16x16x32_bf16(xf, wf[1][kc], acc[1][s], 0, 0, 0);
      }
    }
  }

  if (!isV) {  // Q or K -> [n][c] ushort4 stores
    unsigned short* dst = (m0 < 256) ? Qt : Kt;
    const float scl = (m0 < 256) ? QSCALEf : 1.0f;
#pragma unroll
    for (int g = 0; g < 2; ++g) {
      int cb = ((ob + g * 16) & 255) + lq * 4;
      float b0 = wb[ob + g * 16 + lq * 4 + 0];
      float b1 = wb[ob + g * 16 + lq * 4 + 1];
      float b2 = wb[ob + g * 16 + lq * 4 + 2];
      float b3 = wb[ob + g * 16 + lq * 4 + 3];
#pragma unroll
      for (int s = 0; s < 4; ++s) {
        int n = n0 + s * 16 + l15;
        ushort4 pk;
        pk.x = f2bf((acc[g][s][0] + b0) * scl);
        pk.y = f2bf((acc[g][s][1] + b1) * scl);
        pk.z = f2bf((acc[g][s][2] + b2) * scl);
        pk.w = f2bf((acc[g][s][3] + b3) * scl);
        *(ushort4*)(dst + ((size_t)(b * HWn + n)) * Cn + cb) = pk;
      }
    }
  } else {     // V -> [c][n] ushort4 stores
#pragma unroll
    for (int g = 0; g < 2; ++g) {
      int o = ob + g * 16 + l15;
      int c = o - 512;
      float bias = wb[o];
#pragma unroll
      for (int s = 0; s < 4; ++s) {
        int n = n0 + s * 16 + lq * 4;
        ushort4 pk;
        pk.x = f2bf(acc[g][s][0] + bias);
        pk.y = f2bf(acc[g][s][1] + bias);
        pk.z = f2bf(acc[g][s][2] + bias);
        pk.w = f2bf(acc[g][s][3] + bias);
        *(ushort4*)(Vb + ((size_t)(b * Cn + c)) * HWn + n) = pk;
      }
    }
  }
}

// ---------------- K3: flash attention (R8 structure; epilogue -> tmpT bf16) ----------------
__global__ __launch_bounds__(256, 2)
void attn_kernel(const unsigned short* __restrict__ Qt,
                 const unsigned short* __restrict__ Kt,
                 const unsigned short* __restrict__ Vb,
                 unsigned short* __restrict__ outp) {
  const int bid = blockIdx.x;
  const int b = bid & 7, i0 = (bid >> 3) * 64;
  const int tid = threadIdx.x;
  const int wv = tid >> 6, l = tid & 63;
  const int l15 = l & 15, lq = l >> 4;

  __shared__ unsigned short Ks[8192];  // 16KB
  __shared__ unsigned short Vs[8192];  // 16KB
  char* KsB = (char*)Ks;
  char* VsB = (char*)Vs;

  const unsigned short* Qb = Qt + ((size_t)b * HWn + i0) * Cn;
  const unsigned short* Kb = Kt + (size_t)b * HWn * Cn;
  const unsigned short* Vg = Vb + (size_t)b * Cn * HWn;

  bf16x8 qf[8];
  {
    const unsigned short* qrow = Qb + (size_t)(wv * 16 + l15) * Cn + lq * 8;
#pragma unroll
    for (int kc = 0; kc < 8; ++kc) qf[kc] = *(const bf16x8*)(qrow + kc * 32);
  }

  const int jk = ((tid >> 6) & 1) * 16 + (tid & 15);
  const int ck = (tid >> 7) * 32 + ((tid >> 4) & 3) * 8;
  const int cv = (tid >> 6) * 16 + (tid & 15);
  const int jv = ((tid >> 4) & 3) * 8;
  const unsigned short* gK = Kb + (size_t)jk * Cn + ck;
  const unsigned short* gV = Vg + (size_t)cv * HWn + jv;

  const int laneA = l15 + ((lq & 1) << 5);
  const int laneB = laneA + 16;
  const int shi = lq >> 1;

  bf16x8 kst[4], vst[4];
#pragma unroll
  for (int q = 0; q < 4; ++q) kst[q] = *(const bf16x8*)(gK + q * 64);
#pragma unroll
  for (int q = 0; q < 4; ++q) vst[q] = *(const bf16x8*)(gV + (size_t)q * 64 * HWn);
  gK += 32 * Cn; gV += 32;

  f32x4 o_acc[16];
#pragma unroll
  for (int cs = 0; cs < 16; ++cs) o_acc[cs] = (f32x4)(0.f);
  float m_i = -INFINITY, l_i = 0.f;

#pragma unroll 1
  for (int t = 0; t < 128; ++t) {
#pragma unroll
    for (int q = 0; q < 4; ++q) *(bf16x8*)(KsB + tid * 16 + q * 4096) = kst[q];
#pragma unroll
    for (int q = 0; q < 4; ++q) *(bf16x8*)(VsB + tid * 16 + q * 4096) = vst[q];
    __syncthreads();
    if (t < 127) {
#pragma unroll
      for (int q = 0; q < 4; ++q) kst[q] = *(const bf16x8*)(gK + q * 64);
#pragma unroll
      for (int q = 0; q < 4; ++q) vst[q] = *(const bf16x8*)(gV + (size_t)q * 64 * HWn);
      gK += 32 * Cn; gV += 32;
    }

    f32x4 s0 = (f32x4)(0.f), s1 = (f32x4)(0.f);
#pragma unroll
    for (int kc = 0; kc < 8; ++kc) {
      bf16x8 kf0 = *(const bf16x8*)(KsB + l * 16 + kc * 2048);
      bf16x8 kf1 = *(const bf16x8*)(KsB + l * 16 + kc * 2048 + 1024);
      s0 = __builtin_amdgcn_mfma_f32_16x16x32_bf16(kf0, qf[kc], s0, 0, 0, 0);
      s1 = __builtin_amdgcn_mfma_f32_16x16x32_bf16(kf1, qf[kc], s1, 0, 0, 0);
    }

    float p[2][4];
#pragma unroll
    for (int u = 0; u < 4; ++u) { p[0][u] = s0[u]; p[1][u] = s1[u]; }
    float rm = fmaxf(fmaxf(fmaxf(p[0][0], p[0][1]), fmaxf(p[0][2], p[0][3])),
                     fmaxf(fmaxf(p[1][0], p[1][1]), fmaxf(p[1][2], p[1][3])));
    rm = fmaxf(rm, __shfl_xor(rm, 16));
    rm = fmaxf(rm, __shfl_xor(rm, 32));
    if (!__all(rm - m_i <= RTHR)) {
      float mn = fmaxf(m_i, rm);
      float alpha = __expf(m_i - mn);
      m_i = mn;
      l_i *= alpha;
      float a0 = __shfl(alpha, 4 * lq + 0);
      float a1 = __shfl(alpha, 4 * lq + 1);
      float a2 = __shfl(alpha, 4 * lq + 2);
      float a3 = __shfl(alpha, 4 * lq + 3);
#pragma unroll
      for (int cs = 0; cs < 16; ++cs) {
        o_acc[cs][0] *= a0; o_acc[cs][1] *= a1;
        o_acc[cs][2] *= a2; o_acc[cs][3] *= a3;
      }
    }
    float rs = 0.f;
#pragma unroll
    for (int s = 0; s < 2; ++s)
#pragma unroll
      for (int u = 0; u < 4; ++u) { float e = __expf(p[s][u] - m_i); p[s][u] = e; rs += e; }
    rs += __shfl_xor(rs, 16);
    rs += __shfl_xor(rs, 32);
    l_i += rs;

    int d00 = cvt_pk_bf16(p[0][0], p[0][1]), d01 = cvt_pk_bf16(p[0][2], p[0][3]);
    int d10 = cvt_pk_bf16(p[1][0], p[1][1]), d11 = cvt_pk_bf16(p[1][2], p[1][3]);
    int A00 = __shfl(d00, laneA), A01 = __shfl(d01, laneA);
    int A10 = __shfl(d10, laneA), A11 = __shfl(d11, laneA);
    int B00 = __shfl(d00, laneB), B01 = __shfl(d01, laneB);
    int B10 = __shfl(d10, laneB), B11 = __shfl(d11, laneB);
    union { int w[4]; bf16x8 v; } pa;
    pa.w[0] = shi ? A10 : A00; pa.w[1] = shi ? A11 : A01;
    pa.w[2] = shi ? B10 : B00; pa.w[3] = shi ? B11 : B01;

#pragma unroll
    for (int cs = 0; cs < 16; ++cs) {
      bf16x8 vf = *(const bf16x8*)(VsB + l * 16 + cs * 1024);
      o_acc[cs] = __builtin_amdgcn_mfma_f32_16x16x32_bf16(pa.v, vf, o_acc[cs], 0, 0, 0);
    }
    __syncthreads();
  }

  // ---- epilogue: O /= l, write tmpT bf16 [n][c] ----
  float il = 1.f / l_i;
  float i0v = __shfl(il, 4 * lq + 0);
  float i1v = __shfl(il, 4 * lq + 1);
  float i2v = __shfl(il, 4 * lq + 2);
  float i3v = __shfl(il, 4 * lq + 3);
  unsigned short* ob = outp + (size_t)b * HWn * Cn;
  const int ibase = i0 + wv * 16 + lq * 4;
#pragma unroll
  for (int cs = 0; cs < 16; ++cs) {
    int c = cs * 16 + l15;
    ob[(size_t)(ibase + 0) * Cn + c] = f2bf(o_acc[cs][0] * i0v);
    ob[(size_t)(ibase + 1) * Cn + c] = f2bf(o_acc[cs][1] * i1v);
    ob[(size_t)(ibase + 2) * Cn + c] = f2bf(o_acc[cs][2] * i2v);
    ob[(size_t)(ibase + 3) * Cn + c] = f2bf(o_acc[cs][3] * i3v);
  }
}

// ---------------- K4: out projection, LDS-free bf16 MFMA (swapped) + residual ----------------
__global__ __launch_bounds__(256, 2)
void out_gemm_kernel(const unsigned short* __restrict__ tmpT, const float* __restrict__ w,
                     const float* __restrict__ wb, const float* __restrict__ xres,
                     float* __restrict__ y) {
  const int bid = blockIdx.x;
  const int b = bid & 7, r = bid >> 3;
  const int n0 = (r & 63) * 64, m0 = (r >> 6) * 128;
  const int tid = threadIdx.x;
  const int wv = tid >> 6, l = tid & 63;
  const int l15 = l & 15, lq = l >> 4;
  const int ob = m0 + wv * 32;

  bf16x8 wf[2][8];
#pragma unroll
  for (int g = 0; g < 2; ++g) {
    const float* wr = w + (size_t)(ob + g * 16 + l15) * Cn + lq * 8;
#pragma unroll
    for (int kc = 0; kc < 8; ++kc) {
      float4 a = *(const float4*)(wr + kc * 32);
      float4 c4 = *(const float4*)(wr + kc * 32 + 4);
      union { int w4[4]; bf16x8 v; } u;
      u.w4[0] = cvt_pk_bf16(a.x, a.y);  u.w4[1] = cvt_pk_bf16(a.z, a.w);
      u.w4[2] = cvt_pk_bf16(c4.x, c4.y); u.w4[3] = cvt_pk_bf16(c4.z, c4.w);
      wf[g][kc] = u.v;
    }
  }

  const unsigned short* tb = tmpT + (size_t)b * HWn * Cn + lq * 8;
  f32x4 acc[2][4];
#pragma unroll
  for (int g = 0; g < 2; ++g)
#pragma unroll
    for (int s = 0; s < 4; ++s) acc[g][s] = (f32x4)(0.f);

#pragma unroll
  for (int s = 0; s < 4; ++s) {
    const unsigned short* tp = tb + (size_t)(n0 + s * 16 + l15) * Cn;
#pragma unroll
    for (int kc = 0; kc < 8; ++kc) {
      bf16x8 tf = *(const bf16x8*)(tp + kc * 32);
      acc[0][s] = __builtin_amdgcn_mfma_f32_16x16x32_bf16(tf, wf[0][kc], acc[0][s], 0, 0, 0);
      acc[1][s] = __builtin_amdgcn_mfma_f32_16x16x32_bf16(tf, wf[1][kc], acc[1][s], 0, 0, 0);
    }
  }

#pragma unroll
  for (int g = 0; g < 2; ++g) {
    int o = ob + g * 16 + l15;
    float bias = wb[o];
#pragma unroll
    for (int s = 0; s < 4; ++s) {
      int n = n0 + s * 16 + lq * 4;
      size_t idx = ((size_t)(b * Cn + o)) * HWn + n;
      float4 xr = *(const float4*)(xres + idx);
      float4 out;
      out.x = acc[g][s][0] + bias + xr.x;
      out.y = acc[g][s][1] + bias + xr.y;
      out.z = acc[g][s][2] + bias + xr.z;
      out.w = acc[g][s][3] + bias + xr.w;
      *(float4*)(y + idx) = out;
    }
  }
}

extern "C" void kernel_launch(void* const* d_in, const int* in_sizes, int n_in,
                              void* d_out, int out_size, void* d_ws, size_t ws_size,
                              hipStream_t stream) {
  (void)in_sizes; (void)n_in; (void)out_size; (void)ws_size;
  const float* x     = (const float*)d_in[0];
  const float* gn_w  = (const float*)d_in[1];
  const float* gn_b  = (const float*)d_in[2];
  const float* qkv_w = (const float*)d_in[3];
  const float* qkv_b = (const float*)d_in[4];
  const float* out_w = (const float*)d_in[5];
  const float* out_b = (const float*)d_in[6];
  float* out = (float*)d_out;

  char* ws = (char*)d_ws;
  float* s_aff = (float*)ws;                                   // B*C
  float* t_aff = s_aff + Bn * Cn;                              // B*C
  unsigned short* Qt  = (unsigned short*)(ws + 16384);         // 16MB
  unsigned short* Kt  = Qt  + (size_t)Bn * HWn * Cn;           // 16MB
  unsigned short* Vb  = Kt  + (size_t)Bn * HWn * Cn;           // 16MB
  unsigned short* nxT = Vb  + (size_t)Bn * HWn * Cn;           // 16MB
  unsigned short* tmpT = nxT + (size_t)Bn * HWn * Cn;          // 16MB

  gn_stats_kernel<<<dim3(Bn * Gn), 1024, 0, stream>>>(x, gn_w, gn_b, s_aff, t_aff);
  affine_transpose_kernel<<<dim3(2048), 256, 0, stream>>>(x, s_aff, t_aff, nxT);
  qkv_gemm_kernel<<<dim3(3072), 256, 0, stream>>>(nxT, qkv_w, qkv_b, Qt, Kt, Vb);
  attn_kernel<<<dim3(512), 256, 0, stream>>>(Qt, Kt, Vb, tmpT);
  out_gemm_kernel<<<dim3(1024), 256, 0, stream>>>(tmpT, out_w, out_b, x, out);
}